// Round 4
// baseline (2365.462 us; speedup 1.0000x reference)
//
#include <hip/hip_runtime.h>

#define SEQL 1024
#define BATCHN 128
#define UNITS 256
#define INDIM 128
#define G3 768   // r|u|h gate columns

typedef __attribute__((ext_vector_type(8))) short short8;
typedef __attribute__((ext_vector_type(4))) short short4v;
typedef __attribute__((ext_vector_type(4))) float floatx4;

#define NL2E  -1.4426950408889634f   // -log2(e): r,u gate scale
#define PL2E2  2.8853900817779268f   //  2*log2(e): h gate scale

#define HSTRIDE 272                  // compact h row stride (shorts)
#define XSTR 136                     // proj x-stage row stride (shorts)

__device__ __forceinline__ short f2bf(float f) {
  unsigned u = __float_as_uint(f);
  u += 0x7fff + ((u >> 16) & 1);   // round-to-nearest-even
  return (short)(u >> 16);
}
__device__ __forceinline__ float bf2f(unsigned short s) {
  return __uint_as_float(((unsigned)s) << 16);
}
__device__ __forceinline__ float fexp2(float x) {
#if __has_builtin(__builtin_amdgcn_exp2f)
  return __builtin_amdgcn_exp2f(x);
#else
  return __expf(0.6931471805599453f * x);
#endif
}
__device__ __forceinline__ float frcp(float x) {
#if __has_builtin(__builtin_amdgcn_rcpf)
  return __builtin_amdgcn_rcpf(x);
#else
  return 1.f / x;
#endif
}

// ---------------------------------------------------------------------------
// Kernel A: combined input weight WcB (384x768 bf16, B-frag layout) and
// recurrent weight WhB (256x768 bf16, B-frag layout), gate-scaled so the
// epilogues are pure exp2/rcp:  r,u cols x(-log2e);  h cols x(+2 log2e).
// Frag layout: W[k][n] at ((n*KKmax + kk)*4 + q)*8 + j, kk=k>>5,q=(k>>3)&3,j=k&7.
// ---------------------------------------------------------------------------
__global__ void prep_kernel(const float* __restrict__ iw,   // (128,1792)
                            const float* __restrict__ hw,   // (256,768)
                            short* __restrict__ WcB, short* __restrict__ WhB) {
  int idx = blockIdx.x * 256 + threadIdx.x;
  const int WCN = 384 * G3;
  if (idx < WCN) {
    int k = idx / G3, n = idx % G3;
    int i = k & 127, blkk = k >> 7;      // 0:x_t 1:x_{t-1} 2:x_{t-2}
    int gsel = n >> 8, c = n & 255;      // 0:r 1:u 2:h
    const float* row = iw + (size_t)i * 1792;
    float v;
    if (blkk == 0) {
      v = (gsel == 0) ? row[c] + row[768 + c] + row[1280 + c]
        : (gsel == 1) ? row[256 + c] + row[1024 + c] + row[1536 + c]
                      : row[512 + c];
    } else if (blkk == 1) {
      v = (gsel == 0) ? -(row[768 + c] + 2.f * row[1280 + c])
        : (gsel == 1) ? -(row[1024 + c] + 2.f * row[1536 + c])
                      : 0.f;
    } else {
      v = (gsel == 0) ? row[1280 + c]
        : (gsel == 1) ? row[1536 + c]
                      : 0.f;
    }
    v *= (gsel == 2) ? PL2E2 : NL2E;
    int kk = k >> 5, q = (k >> 3) & 3, j = k & 7;
    WcB[(((n * 12 + kk) * 4 + q) * 8) + j] = f2bf(v);
  } else {
    idx -= WCN;
    if (idx < 256 * G3) {
      int k = idx / G3, n = idx % G3;
      float v = hw[(size_t)k * G3 + n] * ((n >> 8) == 2 ? PL2E2 : NL2E);
      int kk = k >> 5, q = (k >> 3) & 3, j = k & 7;
      WhB[(((n * 8 + kk) * 4 + q) * 8) + j] = f2bf(v);
    }
  }
}

// ---------------------------------------------------------------------------
// Kernel B: input projection, 8 timesteps per block (amortizes WcB reads 8x).
// Block = (mt 16-batch-group, tb 8-t group). x window [t0-2 .. t0+7] staged
// once into LDS (bf16, padded rows); per t an A-frag is built from LDS and
// 36 MFMAs accumulate 768 cols. Output layout = rnn consumption order:
// slab dword g*512 + wv_old*64 + r*16 + ln16 packs cols (wv_old*32+ln16,+16).
// ---------------------------------------------------------------------------
__global__ __launch_bounds__(256) void proj_kernel(const float* __restrict__ x,
                                                   const short* __restrict__ WcB,
                                                   const float* __restrict__ bias,
                                                   unsigned* __restrict__ pre2) {
  __shared__ short xS[10 * 16 * XSTR];  // [tr][bb][c], 43.5 KB
  const int tid = threadIdx.x;
  const int tb = blockIdx.x >> 3;       // 0..127
  const int mt = blockIdx.x & 7;        // 16-row batch group
  const int t0 = tb * 8;

#pragma unroll
  for (int pass = 0; pass < 20; ++pass) {
    int rr = pass * 8 + (tid >> 5);     // 0..159 = tr*16 + bb
    int tr = rr >> 4, bb = rr & 15;
    int c = (tid & 31) * 4;
    int tg = t0 - 2 + tr;
    floatx4 v = {0.f, 0.f, 0.f, 0.f};
    if (tg >= 0)
      v = *(const floatx4*)(x + ((size_t)(mt * 16 + bb) * SEQL + tg) * INDIM + c);
    short4v pk;
#pragma unroll
    for (int j = 0; j < 4; ++j) pk[j] = f2bf(v[j]);
    *(short4v*)&xS[(tr * 16 + bb) * XSTR + c] = pk;
  }
  __syncthreads();

  const int wvp = tid >> 6, lane = tid & 63, ln16 = lane & 15;
  const int qp = lane >> 4;

  for (int i = 0; i < 8; ++i) {
    const int t = t0 + i;
    short8 aF[12];
#pragma unroll
    for (int kk = 0; kk < 12; ++kk) {
      int dt = kk >> 2, cc = kk & 3;
      int tr = i + 2 - dt;
      aF[kk] = *(const short8*)&xS[(tr * 16 + ln16) * XSTR + cc * 32 + qp * 8];
    }
    unsigned* slab = pre2 + (size_t)((mt * 4 + qp) * SEQL + t) * 1536;

#pragma unroll
    for (int ig = 0; ig < 3; ++ig) {
      const int ngrp = wvp * 3 + ig;                 // 0..11 -> 64-col group
      const float sc = (ngrp >= 8) ? PL2E2 : NL2E;
      floatx4 acc[4];
#pragma unroll
      for (int nt = 0; nt < 4; ++nt) {
        float bv = bias[ngrp * 64 + nt * 16 + ln16] * sc;
#pragma unroll
        for (int r = 0; r < 4; ++r) acc[nt][r] = bv;
      }
#pragma unroll
      for (int kk = 0; kk < 12; ++kk) {
#pragma unroll
        for (int nt = 0; nt < 4; ++nt) {
          int n = ngrp * 64 + nt * 16 + ln16;
          short8 w = *(const short8*)(WcB + (((size_t)(n * 12 + kk) * 4 + qp) * 8));
          acc[nt] = __builtin_amdgcn_mfma_f32_16x16x32_bf16(aF[kk], w, acc[nt], 0, 0, 0);
        }
      }
      const int g = ngrp >> 2;                       // gate 0:r 1:u 2:h
#pragma unroll
      for (int p = 0; p < 2; ++p) {                  // nt pair (2p, 2p+1)
        int wvo = (ngrp & 3) * 2 + p;                // consuming 32-col group
#pragma unroll
        for (int r = 0; r < 4; ++r) {
          unsigned lo = (unsigned)(unsigned short)f2bf(acc[2 * p][r]);
          unsigned hi = (unsigned)(unsigned short)f2bf(acc[2 * p + 1][r]);
          slab[g * 512 + wvo * 64 + r * 16 + ln16] = lo | (hi << 16);
        }
      }
    }
  }
}

// ---------------------------------------------------------------------------
// Kernel C: persistent recurrence. 32 WGs x 1024 threads (16 waves, 4/SIMD);
// 4 batch rows per WG; each wave owns 16 columns -> weights are 96 VGPR/wave
// (fits the 128-reg cap so they stay register-resident), and 4 waves/SIMD x
// 2 chains = 8 independent MFMA streams (back-to-back issue).
// h/rh compact 4x256 bf16 in LDS; A[m][k] = h[m&3][k] (broadcast reads).
// ---------------------------------------------------------------------------
__global__ __launch_bounds__(1024) void rnn_kernel(const unsigned* __restrict__ pre2,
                                                   const short* __restrict__ WhB,
                                                   float* __restrict__ out) {
  __shared__ __align__(16) short hFc[4 * HSTRIDE];   // h,  rows 0..3 compact
  __shared__ __align__(16) short rFc[4 * HSTRIDE];   // r*h

  const int tid = threadIdx.x;          // 0..1023
  const int wv = tid >> 6;              // 0..15
  const int lane = tid & 63, ln16 = lane & 15, q = lane >> 4;
  const int row4 = lane & 3;            // A-frag source row (m & 3)
  const int wg = blockIdx.x;            // 0..31

  // persistent weight fragments: this thread's single column nr of each gate
  const int nr = wv * 16 + ln16;
  short8 wR[8], wU[8], wH[8];
#pragma unroll
  for (int kk = 0; kk < 8; ++kk) {
    wR[kk] = *(const short8*)(WhB + (((size_t)(nr * 8 + kk) * 4 + q) * 8));
    wU[kk] = *(const short8*)(WhB + (((size_t)((256 + nr) * 8 + kk) * 4 + q) * 8));
    wH[kk] = *(const short8*)(WhB + (((size_t)((512 + nr) * 8 + kk) * 4 + q) * 8));
  }
  for (int i = tid; i < 4 * HSTRIDE; i += 1024) { hFc[i] = 0; rFc[i] = 0; }

  const floatx4 z4 = {0.f, 0.f, 0.f, 0.f};
  float hq = 0.f;                       // h(row=q, col=nr)

  const unsigned* slab0 = pre2 + (size_t)wg * SEQL * 1536;
  const int ld = (wv >> 1) * 64 + q * 16 + ln16;   // packed dword index
  const int hsel = wv & 1;                          // lo/hi half of dword
  unsigned cur0 = slab0[0 * 512 + ld];
  unsigned cur1 = slab0[1 * 512 + ld];
  unsigned cur2 = slab0[2 * 512 + ld];

  float* outBase = out + ((size_t)(wg * 4 + q) * SEQL) * UNITS + nr;
  const int aoff = row4 * HSTRIDE + q * 8;   // + kk*32 per k-block
  const int woff = q * HSTRIDE + nr;

  __syncthreads();

  for (int t = 0; t < SEQL; ++t) {
    const unsigned* ns = slab0 + (size_t)(t < SEQL - 1 ? t + 1 : t) * 1536;
    unsigned nxt0 = ns[0 * 512 + ld];
    unsigned nxt1 = ns[1 * 512 + ld];
    unsigned nxt2 = ns[2 * 512 + ld];

    // ---- phase A: r,u pre-acts for col nr ----
    floatx4 accR, accU;
    {
      const short8 a0 = *(const short8*)&hFc[aoff];
      accR = __builtin_amdgcn_mfma_f32_16x16x32_bf16(a0, wR[0], z4, 0, 0, 0);
      accU = __builtin_amdgcn_mfma_f32_16x16x32_bf16(a0, wU[0], z4, 0, 0, 0);
    }
#pragma unroll
    for (int kk = 1; kk < 8; ++kk) {
      const short8 a = *(const short8*)&hFc[aoff + kk * 32];
      accR = __builtin_amdgcn_mfma_f32_16x16x32_bf16(a, wR[kk], accR, 0, 0, 0);
      accU = __builtin_amdgcn_mfma_f32_16x16x32_bf16(a, wU[kk], accU, 0, 0, 0);
    }
    float vR = (q == 0) ? accR[0] : (q == 1) ? accR[1] : (q == 2) ? accR[2] : accR[3];
    float vU = (q == 0) ? accU[0] : (q == 1) ? accU[1] : (q == 2) ? accU[2] : accU[3];
    float pR = bf2f((unsigned short)(hsel ? (cur0 >> 16) : (cur0 & 0xffff)));
    float pU = bf2f((unsigned short)(hsel ? (cur1 >> 16) : (cur1 & 0xffff)));
    float rg = frcp(1.f + fexp2(vR + pR));            // sigmoid (scale folded)
    float ug = frcp(1.f + fexp2(vU + pU));
    rFc[woff] = f2bf(rg * hq);
    __syncthreads();

    // ---- phase B: cand for col nr; h update ----
    floatx4 accH;
    {
      const short8 a0 = *(const short8*)&rFc[aoff];
      accH = __builtin_amdgcn_mfma_f32_16x16x32_bf16(a0, wH[0], z4, 0, 0, 0);
    }
#pragma unroll
    for (int kk = 1; kk < 8; ++kk) {
      const short8 a = *(const short8*)&rFc[aoff + kk * 32];
      accH = __builtin_amdgcn_mfma_f32_16x16x32_bf16(a, wH[kk], accH, 0, 0, 0);
    }
    float vH = (q == 0) ? accH[0] : (q == 1) ? accH[1] : (q == 2) ? accH[2] : accH[3];
    float pH = bf2f((unsigned short)(hsel ? (cur2 >> 16) : (cur2 & 0xffff)));
    float cand = 1.f - 2.f * frcp(1.f + fexp2(vH + pH));   // tanh (scale folded)
    float hnew = ug * (hq - cand) + cand;
    hq = hnew;
    hFc[woff] = f2bf(hnew);
    outBase[(size_t)t * UNITS] = hnew;
    cur0 = nxt0; cur1 = nxt1; cur2 = nxt2;
    __syncthreads();
  }
}

extern "C" void kernel_launch(void* const* d_in, const int* in_sizes, int n_in,
                              void* d_out, int out_size, void* d_ws, size_t ws_size,
                              hipStream_t stream) {
  const float* x    = (const float*)d_in[0];
  const float* iw   = (const float*)d_in[1];
  const float* hw   = (const float*)d_in[2];
  const float* bias = (const float*)d_in[3];
  // d_in[4] (constant) is [I;0] — folded analytically, unused.
  float* out = (float*)d_out;

  unsigned* pre2 = (unsigned*)d_ws;                    // 32*1024*1536 dwords = 192 MB
  const size_t preDwords = (size_t)32 * SEQL * 1536;
  short* WcB = (short*)(pre2 + preDwords);             // 384*768 bf16
  short* WhB = WcB + (size_t)384 * G3;                 // 256*768 bf16

  prep_kernel<<<1920, 256, 0, stream>>>(iw, hw, WcB, WhB);
  proj_kernel<<<1024, 256, 0, stream>>>(x, WcB, bias, pre2);
  rnn_kernel<<<32, 1024, 0, stream>>>(pre2, WhB, out);
}